// Round 13
// baseline (324.380 us; speedup 1.0000x reference)
//
#include <hip/hip_runtime.h>
#include <hip/hip_bf16.h>
#include <math.h>

#define NN 50000
#define EE 640000
#define DD 128
#define NREL 8
#define NCLS 16
#define NBUCK (NREL * NN)              // 400000 buckets, key = dst*8 + rel (dst-major)
#define SCAN_NB ((NBUCK + 255) / 256)  // 1563
#define NBIN 64

typedef __attribute__((ext_vector_type(8))) short short8;   // 8 bf16 = 4 VGPRs
typedef __attribute__((ext_vector_type(4))) float f32x4;    // MFMA acc

__device__ __forceinline__ float bflo(unsigned u) { return __uint_as_float(u << 16); }
__device__ __forceinline__ float bfhi(unsigned u) { return __uint_as_float(u & 0xffff0000u); }
__device__ __forceinline__ float bf2f(ushort u) { return __uint_as_float(((unsigned)u) << 16); }
__device__ __forceinline__ ushort f2b(float f) {  // RNE
  unsigned u = __float_as_uint(f);
  u += 0x7fff + ((u >> 16) & 1);
  return (ushort)(u >> 16);
}

// ---------- CSR build (key = dst*8 + rel) ----------

__global__ __launch_bounds__(256) void count_kernel(const int* __restrict__ ei,
                                                    const int* __restrict__ et,
                                                    int* __restrict__ cnt) {
  int t = blockIdx.x * 256 + threadIdx.x;
  if (t < EE) {
    int key = ei[EE + t] * NREL + et[t];
    atomicAdd(&cnt[key], 1);
  }
}

__global__ __launch_bounds__(256) void scan1_kernel(const int* __restrict__ cnt,
                                                    int* __restrict__ off,
                                                    int* __restrict__ bsum) {
  __shared__ int s[256];
  const int tid = threadIdx.x;
  const int i = blockIdx.x * 256 + tid;
  int v = (i < NBUCK) ? cnt[i] : 0;
  s[tid] = v;
  __syncthreads();
#pragma unroll
  for (int o = 1; o < 256; o <<= 1) {
    int t2 = (tid >= o) ? s[tid - o] : 0;
    __syncthreads();
    s[tid] += t2;
    __syncthreads();
  }
  if (i < NBUCK) off[i] = s[tid] - v;
  if (tid == 255) bsum[blockIdx.x] = s[255];
}

__global__ __launch_bounds__(256) void scan2_kernel(const int* __restrict__ bsum,
                                                    int* __restrict__ bpre) {
  __shared__ int s[256];
  __shared__ int carry;
  const int tid = threadIdx.x;
  if (tid == 0) carry = 0;
  __syncthreads();
  const int chunks = (SCAN_NB + 255) / 256;
  for (int c = 0; c < chunks; c++) {
    int idx = c * 256 + tid;
    int v = (idx < SCAN_NB) ? bsum[idx] : 0;
    s[tid] = v;
    __syncthreads();
#pragma unroll
    for (int o = 1; o < 256; o <<= 1) {
      int t2 = (tid >= o) ? s[tid - o] : 0;
      __syncthreads();
      s[tid] += t2;
      __syncthreads();
    }
    if (idx < SCAN_NB) bpre[idx] = carry + s[tid] - v;
    __syncthreads();
    if (tid == 255) carry += s[255];
    __syncthreads();
  }
}

// finalizes off, fills cursor, zeroes the degree-bin histogram
__global__ __launch_bounds__(256) void scan3_kernel(int* __restrict__ off,
                                                    const int* __restrict__ bpre,
                                                    int* __restrict__ cursor,
                                                    int* __restrict__ hist) {
  int i = blockIdx.x * 256 + threadIdx.x;
  if (i < NBUCK) {
    int o = off[i] + bpre[i >> 8];
    off[i] = o;
    cursor[i] = o;
  }
  if (i < NBIN) hist[i] = 0;
  if (i == 0) off[NBUCK] = EE;
}

// rec word0 = src | rel<<16 ; word1 = ew/cnt (pre-divided mean scale)
__global__ __launch_bounds__(256) void bucket_kernel(const int* __restrict__ ei,
                                                     const int* __restrict__ et,
                                                     const float* __restrict__ ew,
                                                     const int* __restrict__ cnt,
                                                     int* __restrict__ cursor,
                                                     uint2* __restrict__ rec) {
  int e = blockIdx.x * 256 + threadIdx.x;
  if (e >= EE) return;
  int r = et[e];
  int key = ei[EE + e] * NREL + r;
  float scale = ew[e] / fmaxf((float)cnt[key], 1.0f);
  int pos = atomicAdd(&cursor[key], 1);
  rec[pos] = make_uint2((unsigned)ei[e] | ((unsigned)r << 16), __float_as_uint(scale));
}

// ---------- node-degree counting sort -> vqueue ----------

__global__ __launch_bounds__(256) void vhist_kernel(const int* __restrict__ off,
                                                    int* __restrict__ hist) {
  __shared__ int lh[NBIN];
  const int tid = threadIdx.x;
  if (tid < NBIN) lh[tid] = 0;
  __syncthreads();
  int v = blockIdx.x * 256 + tid;
  if (v < NN) {
    int deg = off[v * NREL + NREL] - off[v * NREL];
    atomicAdd(&lh[min(deg, NBIN - 1)], 1);
  }
  __syncthreads();
  if (tid < NBIN && lh[tid] > 0) atomicAdd(&hist[tid], lh[tid]);
}

__global__ __launch_bounds__(256) void scan64_kernel(const int* __restrict__ hist,
                                                     int* __restrict__ binCur) {
  __shared__ int s[NBIN];
  const int tid = threadIdx.x;
  if (tid < NBIN) s[tid] = hist[tid];
  __syncthreads();
#pragma unroll
  for (int o = 1; o < NBIN; o <<= 1) {
    int t2 = (tid < NBIN && tid >= o) ? s[tid - o] : 0;
    __syncthreads();
    if (tid < NBIN) s[tid] += t2;
    __syncthreads();
  }
  if (tid < NBIN) binCur[tid] = s[tid] - hist[tid];
}

__global__ __launch_bounds__(256) void vqbuild_kernel(const int* __restrict__ off,
                                                      int* __restrict__ binCur,
                                                      int* __restrict__ vqueue) {
  __shared__ int lh[NBIN];
  __shared__ int lbase[NBIN];
  const int tid = threadIdx.x;
  const int v = blockIdx.x * 256 + tid;
  int bin = -1, lpos = 0;
  if (tid < NBIN) lh[tid] = 0;
  __syncthreads();
  if (v < NN) {
    int deg = off[v * NREL + NREL] - off[v * NREL];
    bin = min(deg, NBIN - 1);
    lpos = atomicAdd(&lh[bin], 1);
  }
  __syncthreads();
  if (tid < NBIN && lh[tid] > 0) lbase[tid] = atomicAdd(&binCur[tid], lh[tid]);
  __syncthreads();
  if (bin >= 0) vqueue[lbase[bin] + lpos] = v;
}

// ---------- pack x (bf16) + W1Tc + W2T ----------
// W1Tc[n*1024 + r*128 + k] = bf16(W1[r][k][n]); W2T[j*128 + k] = bf16(W2[j>>4][k][j&15])
#define XQ (NN * DD / 4)
__global__ __launch_bounds__(256) void pack_kernel(const float* __restrict__ x,
                                                   const float* __restrict__ W1,
                                                   const float* __restrict__ W2,
                                                   ushort* __restrict__ xb,
                                                   ushort* __restrict__ W1Tc,
                                                   ushort* __restrict__ W2T) {
  int t = blockIdx.x * 256 + threadIdx.x;
  if (t < XQ) {
    float4 v = *(const float4*)&x[(size_t)t * 4];
    *(ushort4*)&xb[(size_t)t * 4] = make_ushort4(f2b(v.x), f2b(v.y), f2b(v.z), f2b(v.w));
  } else if (t < XQ + NREL * DD * DD) {
    int t2 = t - XQ;
    int n = t2 >> 10, r = (t2 >> 7) & 7, k = t2 & 127;
    W1Tc[t2] = f2b(W1[r * 16384 + k * 128 + n]);
  } else if (t < XQ + NREL * DD * DD + DD * DD) {
    int t2 = t - XQ - NREL * DD * DD;
    int j = t2 >> 7, k = t2 & 127;
    W2T[t2] = f2b(W2[(j >> 4) * (DD * NCLS) + k * NCLS + (j & 15)]);
  }
}

// ---------- fused layer1+layer2: H2 = bf16( relu(gather(x) @ W1cat) @ W2T^T ) ----------
// Block = 16 nodes, 256 threads (4 waves). 3125 blocks -> ~8 resident blocks/CU
// (32 waves/CU ceiling) and fine-grained load balance. Gather: 16 thr/node x 8
// cols, 2 edges in flight. MFMA: M=16 tile; each wave owns 32 out-cols (acc[2]),
// A fragment shared via LDS broadcast, B straight from L2. Layer-2 GEMM fused.
__global__ __launch_bounds__(256) void fused1_kernel(const int* __restrict__ off,
                                                     const uint2* __restrict__ rec,
                                                     const ushort* __restrict__ xb,
                                                     const ushort* __restrict__ W1Tc,
                                                     const ushort* __restrict__ W2T,
                                                     ushort* __restrict__ H2) {
  __shared__ ushort AsU[16 * 136];     // 4352 B total LDS
  const int tid = threadIdx.x;
  const int m0 = blockIdx.x * 16;
  const int wave = tid >> 6, lane = tid & 63;
  const int lm = lane & 15, lkb = (lane >> 4) * 8;
  const int gn = tid >> 4;          // gather: node 0..15
  const int gc = (tid & 15) * 8;    // gather: col base (8 cols)
  const int v = m0 + gn;

  // hoist the node's 9 contiguous offsets (dst-major key)
  int offv[9];
  if (v < NN) {
    int4 o0 = *(const int4*)&off[v * 8];
    int4 o1 = *(const int4*)&off[v * 8 + 4];
    offv[0] = o0.x; offv[1] = o0.y; offv[2] = o0.z; offv[3] = o0.w;
    offv[4] = o1.x; offv[5] = o1.y; offv[6] = o1.z; offv[7] = o1.w;
    offv[8] = off[v * 8 + 8];
  } else {
#pragma unroll
    for (int i = 0; i < 9; i++) offv[i] = 0;
  }

  f32x4 acc[2];
#pragma unroll
  for (int j = 0; j < 2; j++) acc[j] = (f32x4){0.f, 0.f, 0.f, 0.f};

#pragma unroll
  for (int r = 0; r < NREL; r++) {
    __syncthreads();  // previous chunk's AsU reads complete
    // register gather: 8 cols (1 uint4) per edge, 2 edges in flight
    float g[8];
#pragma unroll
    for (int j = 0; j < 8; j++) g[j] = 0.f;
    {
      int s = offv[r], e = offv[r + 1];
      int i = s;
      for (; i + 2 <= e; i += 2) {
        uint2 q0 = rec[i], q1 = rec[i + 1];
        float sc0 = __uint_as_float(q0.y), sc1 = __uint_as_float(q1.y);
        uint4 h0 = *(const uint4*)&xb[(size_t)(q0.x & 0xffff) * DD + gc];
        uint4 h1 = *(const uint4*)&xb[(size_t)(q1.x & 0xffff) * DD + gc];
        g[0] = fmaf(sc0, bflo(h0.x), g[0]);
        g[1] = fmaf(sc0, bfhi(h0.x), g[1]);
        g[2] = fmaf(sc0, bflo(h0.y), g[2]);
        g[3] = fmaf(sc0, bfhi(h0.y), g[3]);
        g[4] = fmaf(sc0, bflo(h0.z), g[4]);
        g[5] = fmaf(sc0, bfhi(h0.z), g[5]);
        g[6] = fmaf(sc0, bflo(h0.w), g[6]);
        g[7] = fmaf(sc0, bfhi(h0.w), g[7]);
        g[0] = fmaf(sc1, bflo(h1.x), g[0]);
        g[1] = fmaf(sc1, bfhi(h1.x), g[1]);
        g[2] = fmaf(sc1, bflo(h1.y), g[2]);
        g[3] = fmaf(sc1, bfhi(h1.y), g[3]);
        g[4] = fmaf(sc1, bflo(h1.z), g[4]);
        g[5] = fmaf(sc1, bfhi(h1.z), g[5]);
        g[6] = fmaf(sc1, bflo(h1.w), g[6]);
        g[7] = fmaf(sc1, bfhi(h1.w), g[7]);
      }
      if (i < e) {
        uint2 q = rec[i];
        float sc = __uint_as_float(q.y);
        uint4 h = *(const uint4*)&xb[(size_t)(q.x & 0xffff) * DD + gc];
        g[0] = fmaf(sc, bflo(h.x), g[0]);
        g[1] = fmaf(sc, bfhi(h.x), g[1]);
        g[2] = fmaf(sc, bflo(h.y), g[2]);
        g[3] = fmaf(sc, bfhi(h.y), g[3]);
        g[4] = fmaf(sc, bflo(h.z), g[4]);
        g[5] = fmaf(sc, bfhi(h.z), g[5]);
        g[6] = fmaf(sc, bflo(h.w), g[6]);
        g[7] = fmaf(sc, bfhi(h.w), g[7]);
      }
    }
    {
      uint4 u;
      u.x = (unsigned)f2b(g[0]) | ((unsigned)f2b(g[1]) << 16);
      u.y = (unsigned)f2b(g[2]) | ((unsigned)f2b(g[3]) << 16);
      u.z = (unsigned)f2b(g[4]) | ((unsigned)f2b(g[5]) << 16);
      u.w = (unsigned)f2b(g[6]) | ((unsigned)f2b(g[7]) << 16);
      *(uint4*)&AsU[gn * 136 + gc] = u;
    }
    __syncthreads();
    // MFMA: wave owns out-cols [wave*32, wave*32+32); B fragments from L2
#pragma unroll
    for (int k0 = 0; k0 < 128; k0 += 32) {
      short8 a = *(const short8*)&AsU[lm * 136 + k0 + lkb];
      short8 b0 = *(const short8*)&W1Tc[(size_t)(wave * 32 + lm) * 1024 + r * 128 + k0 + lkb];
      short8 b1 = *(const short8*)&W1Tc[(size_t)(wave * 32 + 16 + lm) * 1024 + r * 128 + k0 + lkb];
      acc[0] = __builtin_amdgcn_mfma_f32_16x16x32_bf16(a, b0, acc[0], 0, 0, 0);
      acc[1] = __builtin_amdgcn_mfma_f32_16x16x32_bf16(a, b1, acc[1], 0, 0, 0);
    }
  }

  // ---- epilogue 1: relu -> bf16 A2 tile in LDS ----
  __syncthreads();
  const int rquad = (lane >> 4) * 4;
#pragma unroll
  for (int j = 0; j < 2; j++)
#pragma unroll
    for (int i = 0; i < 4; i++)
      AsU[(rquad + i) * 136 + wave * 32 + j * 16 + lm] = f2b(fmaxf(acc[j][i], 0.f));
  __syncthreads();

  // ---- layer-2 GEMM on the in-LDS A2 tile (W2T from L2) ----
  f32x4 acc2[2];
#pragma unroll
  for (int j = 0; j < 2; j++) acc2[j] = (f32x4){0.f, 0.f, 0.f, 0.f};
#pragma unroll
  for (int k0 = 0; k0 < 128; k0 += 32) {
    short8 a = *(const short8*)&AsU[lm * 136 + k0 + lkb];
    short8 b0 = *(const short8*)&W2T[(size_t)(wave * 32 + lm) * DD + k0 + lkb];
    short8 b1 = *(const short8*)&W2T[(size_t)(wave * 32 + 16 + lm) * DD + k0 + lkb];
    acc2[0] = __builtin_amdgcn_mfma_f32_16x16x32_bf16(a, b0, acc2[0], 0, 0, 0);
    acc2[1] = __builtin_amdgcn_mfma_f32_16x16x32_bf16(a, b1, acc2[1], 0, 0, 0);
  }
  __syncthreads();
#pragma unroll
  for (int j = 0; j < 2; j++)
#pragma unroll
    for (int i = 0; i < 4; i++)
      AsU[(rquad + i) * 136 + wave * 32 + j * 16 + lm] = f2b(acc2[j][i]);
  __syncthreads();
  {
    int row = tid >> 4, c8 = (tid & 15) * 8;
    int gr = m0 + row;
    if (gr < NN) *(uint4*)&H2[(size_t)gr * DD + c8] = *(const uint4*)&AsU[row * 136 + c8];
  }
}

// ---------- gather2 + log_softmax ----------
// 16 nodes/block from degree-sorted queue; 16 lanes/node walk the node's single
// contiguous edge range (rel tag in rec), 2 edges in flight; coalesced 32B H2
// slices; no atomics; fused log-softmax.
__global__ __launch_bounds__(256) void gather2_kernel(const int* __restrict__ off,
                                                      const uint2* __restrict__ rec,
                                                      const ushort* __restrict__ H2,
                                                      const int* __restrict__ vqueue,
                                                      float* __restrict__ out) {
  const int tid = threadIdx.x;
  const int g = tid >> 4, c = tid & 15;
  const int qi = blockIdx.x * 16 + g;
  float acc = 0.f;
  int v = 0;
  if (qi < NN) {
    v = vqueue[qi];
    const int s = off[v * NREL], e = off[v * NREL + NREL];
    int j = s;
    for (; j + 2 <= e; j += 2) {
      uint2 q0 = rec[j], q1 = rec[j + 1];
      ushort h0 = H2[(size_t)(q0.x & 0xffff) * DD + (q0.x >> 16) * NCLS + c];
      ushort h1 = H2[(size_t)(q1.x & 0xffff) * DD + (q1.x >> 16) * NCLS + c];
      acc = fmaf(__uint_as_float(q0.y), bf2f(h0), acc);
      acc = fmaf(__uint_as_float(q1.y), bf2f(h1), acc);
    }
    if (j < e) {
      uint2 q = rec[j];
      acc = fmaf(__uint_as_float(q.y),
                 bf2f(H2[(size_t)(q.x & 0xffff) * DD + (q.x >> 16) * NCLS + c]), acc);
    }
  }
  float m = acc;
#pragma unroll
  for (int mask = 8; mask >= 1; mask >>= 1) m = fmaxf(m, __shfl_xor(m, mask, 16));
  float ex = expf(acc - m);
#pragma unroll
  for (int mask = 8; mask >= 1; mask >>= 1) ex += __shfl_xor(ex, mask, 16);
  if (qi < NN) out[(size_t)v * NCLS + c] = acc - m - logf(ex);
}

extern "C" void kernel_launch(void* const* d_in, const int* in_sizes, int n_in,
                              void* d_out, int out_size, void* d_ws, size_t ws_size,
                              hipStream_t stream) {
  const float* x  = (const float*)d_in[0];
  const int*   ei = (const int*)d_in[1];
  const int*   et = (const int*)d_in[2];
  const float* ew = (const float*)d_in[3];
  const float* W1 = (const float*)d_in[4];
  const float* W2 = (const float*)d_in[5];
  float* out = (float*)d_out;
  float* ws = (float*)d_ws;

  // workspace layout (float-unit offsets; ~36 MB)
  int*    cnt    = (int*)ws;                    // 400000
  int*    off    = (int*)(ws + 400000);         // 400001 (+pad)
  int*    bsum   = (int*)(ws + 800004);         // 1563 (+pad)
  int*    bpre   = (int*)(ws + 801568);         // 1563 (+pad)
  int*    cursor = (int*)(ws + 803132);         // 400000
  int*    hist   = (int*)(ws + 1203132);        // 64
  int*    binCur = (int*)(ws + 1203196);        // 64
  int*    vqueue = (int*)(ws + 1203260);        // 50000
  uint2*  rec    = (uint2*)(ws + 1253260);      // 640000 uint2
  ushort* xb     = (ushort*)(ws + 2533260);     // NN*DD bf16
  ushort* W1Tc   = (ushort*)(ws + 5733260);     // 128*1024 bf16
  ushort* W2T    = (ushort*)(ws + 5798796);     // 128*128 bf16
  ushort* H2     = (ushort*)(ws + 5806988);     // NN*DD bf16

  hipMemsetAsync(cnt, 0, (size_t)NBUCK * sizeof(int), stream);

  count_kernel<<<(EE + 255) / 256, 256, 0, stream>>>(ei, et, cnt);
  scan1_kernel<<<SCAN_NB, 256, 0, stream>>>(cnt, off, bsum);
  scan2_kernel<<<1, 256, 0, stream>>>(bsum, bpre);
  scan3_kernel<<<SCAN_NB, 256, 0, stream>>>(off, bpre, cursor, hist);
  bucket_kernel<<<(EE + 255) / 256, 256, 0, stream>>>(ei, et, ew, cnt, cursor, rec);

  vhist_kernel<<<(NN + 255) / 256, 256, 0, stream>>>(off, hist);
  scan64_kernel<<<1, 256, 0, stream>>>(hist, binCur);
  vqbuild_kernel<<<(NN + 255) / 256, 256, 0, stream>>>(off, binCur, vqueue);

  const int packN = XQ + NREL * DD * DD + DD * DD;
  pack_kernel<<<(packN + 255) / 256, 256, 0, stream>>>(x, W1, W2, xb, W1Tc, W2T);

  fused1_kernel<<<(NN + 15) / 16, 256, 0, stream>>>(off, rec, xb, W1Tc, W2T, H2);
  gather2_kernel<<<(NN + 15) / 16, 256, 0, stream>>>(off, rec, H2, vqueue, out);
}

// Round 14
// 285.190 us; speedup vs baseline: 1.1374x; 1.1374x over previous
//
#include <hip/hip_runtime.h>
#include <hip/hip_bf16.h>
#include <math.h>

#define NN 50000
#define EE 640000
#define DD 128
#define NREL 8
#define NCLS 16
#define NBUCK (NREL * NN)              // 400000 buckets, key = dst*8 + rel (dst-major)
#define SCAN_NB ((NBUCK + 255) / 256)  // 1563
#define NBIN 64

typedef __attribute__((ext_vector_type(8))) short short8;   // 8 bf16 = 4 VGPRs
typedef __attribute__((ext_vector_type(4))) float f32x4;    // MFMA acc

__device__ __forceinline__ float bflo(unsigned u) { return __uint_as_float(u << 16); }
__device__ __forceinline__ float bfhi(unsigned u) { return __uint_as_float(u & 0xffff0000u); }
__device__ __forceinline__ float bf2f(ushort u) { return __uint_as_float(((unsigned)u) << 16); }
__device__ __forceinline__ ushort f2b(float f) {  // RNE
  unsigned u = __float_as_uint(f);
  u += 0x7fff + ((u >> 16) & 1);
  return (ushort)(u >> 16);
}

// ---------- CSR build (key = dst*8 + rel) ----------

__global__ __launch_bounds__(256) void count_kernel(const int* __restrict__ ei,
                                                    const int* __restrict__ et,
                                                    int* __restrict__ cnt) {
  int t = blockIdx.x * 256 + threadIdx.x;
  if (t < EE) {
    int key = ei[EE + t] * NREL + et[t];
    atomicAdd(&cnt[key], 1);
  }
}

__global__ __launch_bounds__(256) void scan1_kernel(const int* __restrict__ cnt,
                                                    int* __restrict__ off,
                                                    int* __restrict__ bsum) {
  __shared__ int s[256];
  const int tid = threadIdx.x;
  const int i = blockIdx.x * 256 + tid;
  int v = (i < NBUCK) ? cnt[i] : 0;
  s[tid] = v;
  __syncthreads();
#pragma unroll
  for (int o = 1; o < 256; o <<= 1) {
    int t2 = (tid >= o) ? s[tid - o] : 0;
    __syncthreads();
    s[tid] += t2;
    __syncthreads();
  }
  if (i < NBUCK) off[i] = s[tid] - v;
  if (tid == 255) bsum[blockIdx.x] = s[255];
}

__global__ __launch_bounds__(256) void scan2_kernel(const int* __restrict__ bsum,
                                                    int* __restrict__ bpre) {
  __shared__ int s[256];
  __shared__ int carry;
  const int tid = threadIdx.x;
  if (tid == 0) carry = 0;
  __syncthreads();
  const int chunks = (SCAN_NB + 255) / 256;
  for (int c = 0; c < chunks; c++) {
    int idx = c * 256 + tid;
    int v = (idx < SCAN_NB) ? bsum[idx] : 0;
    s[tid] = v;
    __syncthreads();
#pragma unroll
    for (int o = 1; o < 256; o <<= 1) {
      int t2 = (tid >= o) ? s[tid - o] : 0;
      __syncthreads();
      s[tid] += t2;
      __syncthreads();
    }
    if (idx < SCAN_NB) bpre[idx] = carry + s[tid] - v;
    __syncthreads();
    if (tid == 255) carry += s[255];
    __syncthreads();
  }
}

// finalizes off, fills cursor, zeroes the degree-bin histogram
__global__ __launch_bounds__(256) void scan3_kernel(int* __restrict__ off,
                                                    const int* __restrict__ bpre,
                                                    int* __restrict__ cursor,
                                                    int* __restrict__ hist) {
  int i = blockIdx.x * 256 + threadIdx.x;
  if (i < NBUCK) {
    int o = off[i] + bpre[i >> 8];
    off[i] = o;
    cursor[i] = o;
  }
  if (i < NBIN) hist[i] = 0;
  if (i == 0) off[NBUCK] = EE;
}

// rec word0 = src | rel<<16 ; word1 = ew/cnt (pre-divided mean scale)
__global__ __launch_bounds__(256) void bucket_kernel(const int* __restrict__ ei,
                                                     const int* __restrict__ et,
                                                     const float* __restrict__ ew,
                                                     const int* __restrict__ cnt,
                                                     int* __restrict__ cursor,
                                                     uint2* __restrict__ rec) {
  int e = blockIdx.x * 256 + threadIdx.x;
  if (e >= EE) return;
  int r = et[e];
  int key = ei[EE + e] * NREL + r;
  float scale = ew[e] / fmaxf((float)cnt[key], 1.0f);
  int pos = atomicAdd(&cursor[key], 1);
  rec[pos] = make_uint2((unsigned)ei[e] | ((unsigned)r << 16), __float_as_uint(scale));
}

// ---------- node-degree counting sort -> vqueue ----------

__global__ __launch_bounds__(256) void vhist_kernel(const int* __restrict__ off,
                                                    int* __restrict__ hist) {
  __shared__ int lh[NBIN];
  const int tid = threadIdx.x;
  if (tid < NBIN) lh[tid] = 0;
  __syncthreads();
  int v = blockIdx.x * 256 + tid;
  if (v < NN) {
    int deg = off[v * NREL + NREL] - off[v * NREL];
    atomicAdd(&lh[min(deg, NBIN - 1)], 1);
  }
  __syncthreads();
  if (tid < NBIN && lh[tid] > 0) atomicAdd(&hist[tid], lh[tid]);
}

__global__ __launch_bounds__(256) void scan64_kernel(const int* __restrict__ hist,
                                                     int* __restrict__ binCur) {
  __shared__ int s[NBIN];
  const int tid = threadIdx.x;
  if (tid < NBIN) s[tid] = hist[tid];
  __syncthreads();
#pragma unroll
  for (int o = 1; o < NBIN; o <<= 1) {
    int t2 = (tid < NBIN && tid >= o) ? s[tid - o] : 0;
    __syncthreads();
    if (tid < NBIN) s[tid] += t2;
    __syncthreads();
  }
  if (tid < NBIN) binCur[tid] = s[tid] - hist[tid];
}

__global__ __launch_bounds__(256) void vqbuild_kernel(const int* __restrict__ off,
                                                      int* __restrict__ binCur,
                                                      int* __restrict__ vqueue) {
  __shared__ int lh[NBIN];
  __shared__ int lbase[NBIN];
  const int tid = threadIdx.x;
  const int v = blockIdx.x * 256 + tid;
  int bin = -1, lpos = 0;
  if (tid < NBIN) lh[tid] = 0;
  __syncthreads();
  if (v < NN) {
    int deg = off[v * NREL + NREL] - off[v * NREL];
    bin = min(deg, NBIN - 1);
    lpos = atomicAdd(&lh[bin], 1);
  }
  __syncthreads();
  if (tid < NBIN && lh[tid] > 0) lbase[tid] = atomicAdd(&binCur[tid], lh[tid]);
  __syncthreads();
  if (bin >= 0) vqueue[lbase[bin] + lpos] = v;
}

// ---------- pack x (bf16) + W1Tc + W2T ----------
// W1Tc[n*1024 + r*128 + k] = bf16(W1[r][k][n]); W2T[j*128 + k] = bf16(W2[j>>4][k][j&15])
#define XQ (NN * DD / 4)
__global__ __launch_bounds__(256) void pack_kernel(const float* __restrict__ x,
                                                   const float* __restrict__ W1,
                                                   const float* __restrict__ W2,
                                                   ushort* __restrict__ xb,
                                                   ushort* __restrict__ W1Tc,
                                                   ushort* __restrict__ W2T) {
  int t = blockIdx.x * 256 + threadIdx.x;
  if (t < XQ) {
    float4 v = *(const float4*)&x[(size_t)t * 4];
    *(ushort4*)&xb[(size_t)t * 4] = make_ushort4(f2b(v.x), f2b(v.y), f2b(v.z), f2b(v.w));
  } else if (t < XQ + NREL * DD * DD) {
    int t2 = t - XQ;
    int n = t2 >> 10, r = (t2 >> 7) & 7, k = t2 & 127;
    W1Tc[t2] = f2b(W1[r * 16384 + k * 128 + n]);
  } else if (t < XQ + NREL * DD * DD + DD * DD) {
    int t2 = t - XQ - NREL * DD * DD;
    int j = t2 >> 7, k = t2 & 127;
    W2T[t2] = f2b(W2[(j >> 4) * (DD * NCLS) + k * NCLS + (j & 15)]);
  }
}

// ---------- fused layer1+layer2: H2 = bf16( relu(gather(x) @ W1cat) @ W2T^T ) ----------
// Block = 32 nodes, 512 threads (8 waves); grid 1563 -> ~4 resident blocks/CU
// (32-wave ceiling) with ~8% quantization tail. Gather: 16 thr/node x 8 cols,
// 2 edges in flight. MFMA: M=32 tile; each wave owns 16 out-cols with 2
// M-fragments (acc[2]); one B fragment per k0 straight from L2. Layer-2 fused.
__global__ __launch_bounds__(512) void fused1_kernel(const int* __restrict__ off,
                                                     const uint2* __restrict__ rec,
                                                     const ushort* __restrict__ xb,
                                                     const ushort* __restrict__ W1Tc,
                                                     const ushort* __restrict__ W2T,
                                                     ushort* __restrict__ H2) {
  __shared__ ushort AsU[32 * 136];     // 8704 B total LDS
  const int tid = threadIdx.x;
  const int m0 = blockIdx.x * 32;
  const int wave = tid >> 6, lane = tid & 63;
  const int lm = lane & 15, lkb = (lane >> 4) * 8;
  const int gn = tid >> 4;          // gather: node 0..31
  const int gc = (tid & 15) * 8;    // gather: col base (8 cols)
  const int v = m0 + gn;

  // hoist the node's 9 contiguous offsets (dst-major key)
  int offv[9];
  if (v < NN) {
    int4 o0 = *(const int4*)&off[v * 8];
    int4 o1 = *(const int4*)&off[v * 8 + 4];
    offv[0] = o0.x; offv[1] = o0.y; offv[2] = o0.z; offv[3] = o0.w;
    offv[4] = o1.x; offv[5] = o1.y; offv[6] = o1.z; offv[7] = o1.w;
    offv[8] = off[v * 8 + 8];
  } else {
#pragma unroll
    for (int i = 0; i < 9; i++) offv[i] = 0;
  }

  f32x4 acc[2];
#pragma unroll
  for (int j = 0; j < 2; j++) acc[j] = (f32x4){0.f, 0.f, 0.f, 0.f};

#pragma unroll
  for (int r = 0; r < NREL; r++) {
    __syncthreads();  // previous chunk's AsU reads complete
    // register gather: 8 cols (1 uint4) per edge, 2 edges in flight
    float g[8];
#pragma unroll
    for (int j = 0; j < 8; j++) g[j] = 0.f;
    {
      int s = offv[r], e = offv[r + 1];
      int i = s;
      for (; i + 2 <= e; i += 2) {
        uint2 q0 = rec[i], q1 = rec[i + 1];
        float sc0 = __uint_as_float(q0.y), sc1 = __uint_as_float(q1.y);
        uint4 h0 = *(const uint4*)&xb[(size_t)(q0.x & 0xffff) * DD + gc];
        uint4 h1 = *(const uint4*)&xb[(size_t)(q1.x & 0xffff) * DD + gc];
        g[0] = fmaf(sc0, bflo(h0.x), g[0]);
        g[1] = fmaf(sc0, bfhi(h0.x), g[1]);
        g[2] = fmaf(sc0, bflo(h0.y), g[2]);
        g[3] = fmaf(sc0, bfhi(h0.y), g[3]);
        g[4] = fmaf(sc0, bflo(h0.z), g[4]);
        g[5] = fmaf(sc0, bfhi(h0.z), g[5]);
        g[6] = fmaf(sc0, bflo(h0.w), g[6]);
        g[7] = fmaf(sc0, bfhi(h0.w), g[7]);
        g[0] = fmaf(sc1, bflo(h1.x), g[0]);
        g[1] = fmaf(sc1, bfhi(h1.x), g[1]);
        g[2] = fmaf(sc1, bflo(h1.y), g[2]);
        g[3] = fmaf(sc1, bfhi(h1.y), g[3]);
        g[4] = fmaf(sc1, bflo(h1.z), g[4]);
        g[5] = fmaf(sc1, bfhi(h1.z), g[5]);
        g[6] = fmaf(sc1, bflo(h1.w), g[6]);
        g[7] = fmaf(sc1, bfhi(h1.w), g[7]);
      }
      if (i < e) {
        uint2 q = rec[i];
        float sc = __uint_as_float(q.y);
        uint4 h = *(const uint4*)&xb[(size_t)(q.x & 0xffff) * DD + gc];
        g[0] = fmaf(sc, bflo(h.x), g[0]);
        g[1] = fmaf(sc, bfhi(h.x), g[1]);
        g[2] = fmaf(sc, bflo(h.y), g[2]);
        g[3] = fmaf(sc, bfhi(h.y), g[3]);
        g[4] = fmaf(sc, bflo(h.z), g[4]);
        g[5] = fmaf(sc, bfhi(h.z), g[5]);
        g[6] = fmaf(sc, bflo(h.w), g[6]);
        g[7] = fmaf(sc, bfhi(h.w), g[7]);
      }
    }
    {
      uint4 u;
      u.x = (unsigned)f2b(g[0]) | ((unsigned)f2b(g[1]) << 16);
      u.y = (unsigned)f2b(g[2]) | ((unsigned)f2b(g[3]) << 16);
      u.z = (unsigned)f2b(g[4]) | ((unsigned)f2b(g[5]) << 16);
      u.w = (unsigned)f2b(g[6]) | ((unsigned)f2b(g[7]) << 16);
      *(uint4*)&AsU[gn * 136 + gc] = u;
    }
    __syncthreads();
    // MFMA: wave owns out-cols [wave*16, wave*16+16); 2 M-fragments; B from L2
#pragma unroll
    for (int k0 = 0; k0 < 128; k0 += 32) {
      short8 a0 = *(const short8*)&AsU[lm * 136 + k0 + lkb];
      short8 a1 = *(const short8*)&AsU[(16 + lm) * 136 + k0 + lkb];
      short8 b = *(const short8*)&W1Tc[(size_t)(wave * 16 + lm) * 1024 + r * 128 + k0 + lkb];
      acc[0] = __builtin_amdgcn_mfma_f32_16x16x32_bf16(a0, b, acc[0], 0, 0, 0);
      acc[1] = __builtin_amdgcn_mfma_f32_16x16x32_bf16(a1, b, acc[1], 0, 0, 0);
    }
  }

  // ---- epilogue 1: relu -> bf16 A2 tile in LDS ----
  __syncthreads();
  const int rquad = (lane >> 4) * 4;
#pragma unroll
  for (int j = 0; j < 2; j++)
#pragma unroll
    for (int i = 0; i < 4; i++)
      AsU[(j * 16 + rquad + i) * 136 + wave * 16 + lm] = f2b(fmaxf(acc[j][i], 0.f));
  __syncthreads();

  // ---- layer-2 GEMM on the in-LDS A2 tile (W2T from L2) ----
  f32x4 acc2[2];
#pragma unroll
  for (int j = 0; j < 2; j++) acc2[j] = (f32x4){0.f, 0.f, 0.f, 0.f};
#pragma unroll
  for (int k0 = 0; k0 < 128; k0 += 32) {
    short8 a0 = *(const short8*)&AsU[lm * 136 + k0 + lkb];
    short8 a1 = *(const short8*)&AsU[(16 + lm) * 136 + k0 + lkb];
    short8 b = *(const short8*)&W2T[(size_t)(wave * 16 + lm) * DD + k0 + lkb];
    acc2[0] = __builtin_amdgcn_mfma_f32_16x16x32_bf16(a0, b, acc2[0], 0, 0, 0);
    acc2[1] = __builtin_amdgcn_mfma_f32_16x16x32_bf16(a1, b, acc2[1], 0, 0, 0);
  }
  __syncthreads();
#pragma unroll
  for (int j = 0; j < 2; j++)
#pragma unroll
    for (int i = 0; i < 4; i++)
      AsU[(j * 16 + rquad + i) * 136 + wave * 16 + lm] = f2b(acc2[j][i]);
  __syncthreads();
  {
    int row = tid >> 4, c8 = (tid & 15) * 8;   // 512 segs = 32 rows x 16 col-chunks
    int gr = m0 + row;
    if (gr < NN) *(uint4*)&H2[(size_t)gr * DD + c8] = *(const uint4*)&AsU[row * 136 + c8];
  }
}

// ---------- gather2 + log_softmax ----------
// 16 nodes/block from degree-sorted queue; 16 lanes/node walk the node's single
// contiguous edge range (rel tag in rec), 2 edges in flight; coalesced 32B H2
// slices; no atomics; fused log-softmax.
__global__ __launch_bounds__(256) void gather2_kernel(const int* __restrict__ off,
                                                      const uint2* __restrict__ rec,
                                                      const ushort* __restrict__ H2,
                                                      const int* __restrict__ vqueue,
                                                      float* __restrict__ out) {
  const int tid = threadIdx.x;
  const int g = tid >> 4, c = tid & 15;
  const int qi = blockIdx.x * 16 + g;
  float acc = 0.f;
  int v = 0;
  if (qi < NN) {
    v = vqueue[qi];
    const int s = off[v * NREL], e = off[v * NREL + NREL];
    int j = s;
    for (; j + 2 <= e; j += 2) {
      uint2 q0 = rec[j], q1 = rec[j + 1];
      ushort h0 = H2[(size_t)(q0.x & 0xffff) * DD + (q0.x >> 16) * NCLS + c];
      ushort h1 = H2[(size_t)(q1.x & 0xffff) * DD + (q1.x >> 16) * NCLS + c];
      acc = fmaf(__uint_as_float(q0.y), bf2f(h0), acc);
      acc = fmaf(__uint_as_float(q1.y), bf2f(h1), acc);
    }
    if (j < e) {
      uint2 q = rec[j];
      acc = fmaf(__uint_as_float(q.y),
                 bf2f(H2[(size_t)(q.x & 0xffff) * DD + (q.x >> 16) * NCLS + c]), acc);
    }
  }
  float m = acc;
#pragma unroll
  for (int mask = 8; mask >= 1; mask >>= 1) m = fmaxf(m, __shfl_xor(m, mask, 16));
  float ex = expf(acc - m);
#pragma unroll
  for (int mask = 8; mask >= 1; mask >>= 1) ex += __shfl_xor(ex, mask, 16);
  if (qi < NN) out[(size_t)v * NCLS + c] = acc - m - logf(ex);
}

extern "C" void kernel_launch(void* const* d_in, const int* in_sizes, int n_in,
                              void* d_out, int out_size, void* d_ws, size_t ws_size,
                              hipStream_t stream) {
  const float* x  = (const float*)d_in[0];
  const int*   ei = (const int*)d_in[1];
  const int*   et = (const int*)d_in[2];
  const float* ew = (const float*)d_in[3];
  const float* W1 = (const float*)d_in[4];
  const float* W2 = (const float*)d_in[5];
  float* out = (float*)d_out;
  float* ws = (float*)d_ws;

  // workspace layout (float-unit offsets; ~36 MB)
  int*    cnt    = (int*)ws;                    // 400000
  int*    off    = (int*)(ws + 400000);         // 400001 (+pad)
  int*    bsum   = (int*)(ws + 800004);         // 1563 (+pad)
  int*    bpre   = (int*)(ws + 801568);         // 1563 (+pad)
  int*    cursor = (int*)(ws + 803132);         // 400000
  int*    hist   = (int*)(ws + 1203132);        // 64
  int*    binCur = (int*)(ws + 1203196);        // 64
  int*    vqueue = (int*)(ws + 1203260);        // 50000
  uint2*  rec    = (uint2*)(ws + 1253260);      // 640000 uint2
  ushort* xb     = (ushort*)(ws + 2533260);     // NN*DD bf16
  ushort* W1Tc   = (ushort*)(ws + 5733260);     // 128*1024 bf16
  ushort* W2T    = (ushort*)(ws + 5798796);     // 128*128 bf16
  ushort* H2     = (ushort*)(ws + 5806988);     // NN*DD bf16

  hipMemsetAsync(cnt, 0, (size_t)NBUCK * sizeof(int), stream);

  count_kernel<<<(EE + 255) / 256, 256, 0, stream>>>(ei, et, cnt);
  scan1_kernel<<<SCAN_NB, 256, 0, stream>>>(cnt, off, bsum);
  scan2_kernel<<<1, 256, 0, stream>>>(bsum, bpre);
  scan3_kernel<<<SCAN_NB, 256, 0, stream>>>(off, bpre, cursor, hist);
  bucket_kernel<<<(EE + 255) / 256, 256, 0, stream>>>(ei, et, ew, cnt, cursor, rec);

  vhist_kernel<<<(NN + 255) / 256, 256, 0, stream>>>(off, hist);
  scan64_kernel<<<1, 256, 0, stream>>>(hist, binCur);
  vqbuild_kernel<<<(NN + 255) / 256, 256, 0, stream>>>(off, binCur, vqueue);

  const int packN = XQ + NREL * DD * DD + DD * DD;
  pack_kernel<<<(packN + 255) / 256, 256, 0, stream>>>(x, W1, W2, xb, W1Tc, W2T);

  fused1_kernel<<<(NN + 31) / 32, 512, 0, stream>>>(off, rec, xb, W1Tc, W2T, H2);
  gather2_kernel<<<(NN + 15) / 16, 256, 0, stream>>>(off, rec, H2, vqueue, out);
}